// Round 14
// baseline (150.338 us; speedup 1.0000x reference)
//
#include <hip/hip_runtime.h>
#include <hip/hip_bf16.h>

#define T_IN   16
#define T_OUT  25
#define BHERO  4096
#define K_NBR  32
#define N_NBR  (BHERO * K_NBR)
#define ENC    64
#define DEC    128
#define DYN    32
#define EMB    32
#define HEROES 8          // real heroes/WG; MFMA rows 8-15 duplicate rows 0-7

#define EMROW  40         // emb row: 32 bf16 + 8 pad (80 B)
#define HROW   72         // encoder h row: 64 bf16 + 8 pad (144 B)
#define RROW   40         // rela row: 32 bf16 + 8 pad (80 B)
#define DROW   136        // decoder h row: 128 bf16 + 8 pad (272 B)

// ---- LDS layout (flat; 45.1 KB total -> 2 WGs/CU) ----
#define OFF_HRING  20480
#define OFF_RELA   25088
#define OFF_PMAX   27648
#define OFF_RINGD  31744
#define OFF_ENC    40448
#define OFF_WOP    44800
#define OFF_WIP    45824
#define OFF_BIP    46080
#define OFF_BOP    46208
#define LDS_TOTAL  46216

#define L2E 1.44269504f   // log2(e); gate pre-scales fold the exp-arg mul into W/b

typedef __attribute__((ext_vector_type(8))) short bf16x8;   // 8 bf16 in 4 VGPRs
typedef __attribute__((ext_vector_type(4))) float f32x4;    // MFMA 16x16 C/D frag

__device__ __forceinline__ float lrelu(float x) { return x >= 0.f ? x : 0.1f * x; }
__device__ __forceinline__ float rcpf(float x)  { return __builtin_amdgcn_rcpf(x); }
__device__ __forceinline__ float ex2(float x)   { return __builtin_amdgcn_exp2f(x); }
__device__ __forceinline__ unsigned pk2(float lo, float hi) {
    __hip_bfloat162 p = __float22bfloat162_rn(make_float2(lo, hi));
    unsigned u; __builtin_memcpy(&u, &p, 4); return u;
}
__device__ __forceinline__ bf16x8 mk_frag(float4 f0, float4 f1) {
    uint4 v = { pk2(f0.x, f0.y), pk2(f0.z, f0.w), pk2(f1.x, f1.y), pk2(f1.z, f1.w) };
    bf16x8 r; __builtin_memcpy(&r, &v, 16); return r;
}
__device__ __forceinline__ bf16x8 mk_frag_s(float4 f0, float4 f1, float s) {
    uint4 v = { pk2(f0.x*s, f0.y*s), pk2(f0.z*s, f0.w*s), pk2(f1.x*s, f1.y*s), pk2(f1.z*s, f1.w*s) };
    bf16x8 r; __builtin_memcpy(&r, &v, 16); return r;
}
__device__ __forceinline__ float bf2f(short s) {
    return __uint_as_float(((unsigned)(unsigned short)s) << 16);
}
// Fused LSTM cell update on PRESCALED gates (i,f,o x L2E; g x 2*L2E). 5 exp + 3 rcp.
__device__ __forceinline__ float2 cell_update(float gi, float gf, float gg, float go, float c) {
    float ea = ex2(-gi);
    float ef = ex2(-gf);
    float eb = ex2(-gg);
    float eo = ex2(-go);
    float ff = rcpf(1.f + ef);
    float ig = (1.f - eb) * rcpf((1.f + ea) * (1.f + eb));
    float cc = fmaf(ff, c, ig);
    float ec = ex2(-2.f * L2E * cc);
    float h  = (1.f - ec) * rcpf((1.f + eo) * (1.f + ec));
    return make_float2(h, cc);
}

// ====== fused highwayNet fwd: 512 WGs x 512 threads, 8 heroes/WG, 2 WGs/CU ======
__global__ __launch_bounds__(512, 4) void highway_fused(
    const float* __restrict__ hist,  const float* __restrict__ nbrs,
    const float* __restrict__ Wip,   const float* __restrict__ bip,
    const float* __restrict__ WihE,  const float* __restrict__ WhhE,
    const float* __restrict__ bihE,  const float* __restrict__ bhhE,
    const float* __restrict__ Wdyn,  const float* __restrict__ bdyn,
    const float* __restrict__ Wnbr,  const float* __restrict__ bnbr,
    const float* __restrict__ WihD,  const float* __restrict__ WhhD,
    const float* __restrict__ bihD,  const float* __restrict__ bhhD,
    const float* __restrict__ Wop,   const float* __restrict__ bop,
    const int*   __restrict__ seg,
    float* __restrict__ fut)                        // [T_OUT][BHERO][2]
{
    __shared__ __align__(16) char lds_raw[LDS_TOTAL];
    auto embs   = (short (*)[16][EMROW])  lds_raw;                  // [16][16][EMROW] (rows 8-15 dup)
    auto hringE = (short (*)[16][HROW])  (lds_raw + OFF_HRING);     // [2][16][HROW]  (rows 8-15 dup)
    auto rela2  = (short (*)[16][RROW])  (lds_raw + OFF_RELA);      // [2][16][RROW]  rolling tiles
    auto pmax   = (float (*)[ENC])       (lds_raw + OFF_PMAX);      // [16][64]
    auto ringD  = (short (*)[16][DROW])  (lds_raw + OFF_RINGD);     // [2][16][DROW]  (rows 8-15 dup)
    auto enc_s  = (float (*)[68])        (lds_raw + OFF_ENC);       // [16][68]       (rows 8-15 dup)
    auto wop_s  = (float (*)[DEC])       (lds_raw + OFF_WOP);       // [2][128]
    auto wip_s  = (float (*)[2])         (lds_raw + OFF_WIP);       // [32][2]
    auto bip_s  = (float*)               (lds_raw + OFF_BIP);       // [32]
    auto bop_s  = (float*)               (lds_raw + OFF_BOP);       // [2]

    const int b0  = blockIdx.x * HEROES;
    const int n0  = blockIdx.x * (HEROES * K_NBR);  // 256 nbr rows per WG
    const int tid = threadIdx.x;
    const int w = tid >> 6, l = tid & 63, r = l & 15, lg = l >> 4;

    // ---------------- P0: consts, zero hringE slab 0, frag prologues ----------------
    if (tid < EMB) {
        wip_s[tid][0] = Wip[2 * tid];
        wip_s[tid][1] = Wip[2 * tid + 1];
        bip_s[tid]    = bip[tid];
    }
    if (tid < 2 * DEC) wop_s[tid >> 7][tid & 127] = Wop[tid];
    if (tid < 2)       bop_s[tid] = bop[tid];
    for (int i = tid; i < 16 * HROW; i += 512) ((short*)hringE[0])[i] = 0;

    // encoder B-frags (waves 0-3, prescaled) / nbr B-frag (waves 4-7: wave i -> col-tile i)
    bf16x8 BfE[4][3];
    float  biasE[4];
    bf16x8 BfN;
    float  biasn = 0.f;
    if (tid < 256) {
        #pragma unroll
        for (int j = 0; j < 4; ++j) {
            const float sj  = (j == 2) ? (2.f * L2E) : L2E;
            const int   col = j * ENC + w * 16 + r;
            biasE[j] = (bihE[col] + bhhE[col]) * sj;
            #pragma unroll
            for (int c = 0; c < 3; ++c) {
                const float* src = (c == 0) ? (WihE + (size_t)col * EMB + 8 * lg)
                                            : (WhhE + (size_t)col * ENC + (c - 1) * 32 + 8 * lg);
                BfE[j][c] = mk_frag_s(*(const float4*)src, *(const float4*)(src + 4), sj);
            }
        }
    } else {
        const int col = (w - 4) * 16 + r;
        biasn = bnbr[col];
        const float* src = Wnbr + (size_t)col * (2 * T_IN) + 8 * lg;
        BfN = mk_frag(*(const float4*)src, *(const float4*)(src + 4));
    }
    __syncthreads();                                // consts + hringE0 ready

    // ---------------- P1: emb prefill (waves 0-3) | rela tile 0 + pipeline prime (waves 4-7) ----------------
    float2 c_h0 = {}, c_v0 = {};                    // tile t+1 data (waves 4-7)
    int    sg_c = 0;                                // seg for tile t+2
    if (tid < 256) {
        const int task = tid >> 1;                  // 128 tasks: (t, m 0..7)
        const int t = task >> 3, m = task & 7;
        const int j0 = (tid & 1) * 16;
        float2 hv = *(const float2*)&hist[((size_t)t * BHERO + b0 + m) * 2];
        #pragma unroll
        for (int jb = 0; jb < 2; ++jb) {
            float e[8];
            #pragma unroll
            for (int q = 0; q < 8; ++q) {
                int j = j0 + jb * 8 + q;
                e[q] = lrelu(hv.x * wip_s[j][0] + hv.y * wip_s[j][1] + bip_s[j]);
            }
            uint4 v = { pk2(e[0],e[1]), pk2(e[2],e[3]), pk2(e[4],e[5]), pk2(e[6],e[7]) };
            __builtin_memcpy(&embs[t][m][j0 + jb * 8], &v, 16);
            __builtin_memcpy(&embs[t][m + 8][j0 + jb * 8], &v, 16);
        }
    } else {
        const int x    = tid - 256;
        const int nloc = x & 15;                    // row within tile
        const int ts   = x >> 4;                    // 0..15
        {   // tile 0: load + write now
            const int hb = seg[n0 + nloc];
            float2 h0 = *(const float2*)&hist[((size_t)ts * BHERO + hb) * 2];
            float2 v0 = *(const float2*)&nbrs[((size_t)ts * N_NBR + n0 + nloc) * 2];
            ((unsigned*)&rela2[0][nloc][0])[ts] = pk2(h0.x - v0.x, h0.y - v0.y);
        }
        {   // tile 1: issue loads into regs (consumed at iter 0)
            const int n  = 16 + nloc;
            const int hb = seg[n0 + n];
            c_h0 = *(const float2*)&hist[((size_t)ts * BHERO + hb) * 2];
            c_v0 = *(const float2*)&nbrs[((size_t)ts * N_NBR + n0 + n) * 2];
        }
        sg_c = seg[n0 + 32 + nloc];                 // seg for tile 2
    }
    f32x4 cstE = {0.f, 0.f, 0.f, 0.f};              // cell: hero (4*lg+q)&7, unit w*16+r
    __syncthreads();                                // emb + rela tile 0 ready

    // ---------------- P2: encoder LSTM (waves 0-3) || pipelined nbr stage+GEMM (waves 4-7) ----------------
    {
        const int x    = tid - 256;                 // waves 4-7
        const int nloc = x & 15;
        const int ts   = x >> 4;
        #pragma unroll 1
        for (int t = 0; t < T_IN; ++t) {
            const int cur = t & 1, nxt = cur ^ 1;
            if (tid < 256) {
                bf16x8 a0 = *(const bf16x8*)&embs[t][r][8 * lg];
                bf16x8 a1 = *(const bf16x8*)&hringE[cur][r][8 * lg];
                bf16x8 a2 = *(const bf16x8*)&hringE[cur][r][32 + 8 * lg];
                f32x4 acc[4];
                #pragma unroll
                for (int j = 0; j < 4; ++j) {
                    f32x4 aA = (f32x4){biasE[j], biasE[j], biasE[j], biasE[j]};
                    f32x4 aB = (f32x4){0.f, 0.f, 0.f, 0.f};
                    aA = __builtin_amdgcn_mfma_f32_16x16x32_bf16(a0, BfE[j][0], aA, 0, 0, 0);
                    aB = __builtin_amdgcn_mfma_f32_16x16x32_bf16(a1, BfE[j][1], aB, 0, 0, 0);
                    aA = __builtin_amdgcn_mfma_f32_16x16x32_bf16(a2, BfE[j][2], aA, 0, 0, 0);
                    acc[j] = aA + aB;
                }
                float hq[4];
                #pragma unroll
                for (int q = 0; q < 4; ++q) {
                    float2 hc = cell_update(acc[0][q], acc[1][q], acc[2][q], acc[3][q], cstE[q]);
                    hq[q]   = hc.x;
                    cstE[q] = hc.y;
                }
                // rows 4lg+q (8-15 are the dup copies; values identical by construction)
                unsigned u01 = pk2(hq[0], hq[1]), u23 = pk2(hq[2], hq[3]);
                short* wp = &hringE[nxt][4 * lg][w * 16 + r];
                wp[0 * HROW] = (short)u01; wp[1 * HROW] = (short)(u01 >> 16);
                wp[2 * HROW] = (short)u23; wp[3 * HROW] = (short)(u23 >> 16);
            } else {
                float2 n_h0 = {}, n_v0 = {};
                int    sg_n = 0;
                if (t < T_IN - 2) {                 // issue tile t+2 loads
                    const int n = 16 * (t + 2) + nloc;
                    n_h0 = *(const float2*)&hist[((size_t)ts * BHERO + sg_c) * 2];
                    n_v0 = *(const float2*)&nbrs[((size_t)ts * N_NBR + n0 + n) * 2];
                }
                if (t < T_IN - 3) sg_n = seg[n0 + 16 * (t + 3) + nloc];
                if (t < T_IN - 1)                   // write tile t+1 from regs (latency hidden)
                    ((unsigned*)&rela2[nxt][nloc][0])[ts] = pk2(c_h0.x - c_v0.x, c_h0.y - c_v0.y);
                // GEMM tile t: wave i = w-4 -> col-tile i
                bf16x8 a = *(const bf16x8*)&rela2[cur][r][8 * lg];
                f32x4 acc = {biasn, biasn, biasn, biasn};
                acc = __builtin_amdgcn_mfma_f32_16x16x32_bf16(a, BfN, acc, 0, 0, 0);
                float m4 = fmaxf(fmaxf(acc[0], acc[1]), fmaxf(acc[2], acc[3]));
                m4 = fmaxf(m4, __shfl_xor(m4, 16));
                m4 = fmaxf(m4, __shfl_xor(m4, 32));
                if (l < 16) pmax[t][(w - 4) * 16 + r] = m4;
                c_h0 = n_h0; c_v0 = n_v0; sg_c = sg_n;
            }
            __syncthreads();                        // h(t+1) + tile t+1 + pmax t ready
        }
    }

    // ---------------- P3: enc_s = [hist_e | scene_d] (dup rows), zero ringD slab 0 ----------------
    {
        const int m = tid >> 6, col = tid & 63;     // 512 tasks: (m 0..7, col 0..63)
        const float* wd = Wdyn + (size_t)(col & 31) * ENC;
        float a = bdyn[col & 31];
        if (col < 32) {
            const short* hp = &hringE[0][m][0];     // final h: slab (T_IN&1)=0
            #pragma unroll
            for (int kb = 0; kb < 8; ++kb) {
                bf16x8 hv = *(const bf16x8*)(hp + kb * 8);
                #pragma unroll
                for (int e = 0; e < 8; ++e)
                    a = fmaf(bf2f(hv[e]), wd[kb * 8 + e], a);
            }
        } else {
            #pragma unroll
            for (int kb = 0; kb < 16; ++kb) {
                float4 p0 = *(const float4*)&pmax[2 * m][kb * 4];
                float4 p1 = *(const float4*)&pmax[2 * m + 1][kb * 4];
                a = fmaf(lrelu(fmaxf(p0.x, p1.x)), wd[kb * 4 + 0], a);
                a = fmaf(lrelu(fmaxf(p0.y, p1.y)), wd[kb * 4 + 1], a);
                a = fmaf(lrelu(fmaxf(p0.z, p1.z)), wd[kb * 4 + 2], a);
                a = fmaf(lrelu(fmaxf(p0.w, p1.w)), wd[kb * 4 + 3], a);
            }
        }
        float av = lrelu(a);
        enc_s[m][col]     = av;
        enc_s[m + 8][col] = av;
        for (int i = tid; i < 16 * DROW; i += 512) ((short*)ringD[0])[i] = 0;
    }
    __syncthreads();                                // enc_s + ringD0 ready

    // ---------------- P4: decoder frags (prescaled) + xw prologue + 25-step LSTM + inline head ----------------
    const int u0 = w * 16;
    bf16x8 BfD[4][4];
    float  biasD[4];
    #pragma unroll
    for (int j = 0; j < 4; ++j) {
        const float sj  = (j == 2) ? (2.f * L2E) : L2E;
        const int   col = j * DEC + u0 + r;
        biasD[j] = (bihD[col] + bhhD[col]) * sj;
        #pragma unroll
        for (int c = 0; c < 4; ++c) {
            const float* src = WhhD + (size_t)col * DEC + c * 32 + 8 * lg;
            BfD[j][c] = mk_frag_s(*(const float4*)src, *(const float4*)(src + 4), sj);
        }
    }
    f32x4 xwf[4];
    {
        bf16x8 aE[2];
        #pragma unroll
        for (int c = 0; c < 2; ++c) {
            float4 f0 = *(const float4*)&enc_s[r][c * 32 + 8 * lg];
            float4 f1 = *(const float4*)&enc_s[r][c * 32 + 8 * lg + 4];
            aE[c] = mk_frag(f0, f1);
        }
        #pragma unroll
        for (int j = 0; j < 4; ++j) {
            const float sj  = (j == 2) ? (2.f * L2E) : L2E;
            const int   col = j * DEC + u0 + r;
            f32x4 a = {biasD[j], biasD[j], biasD[j], biasD[j]};
            #pragma unroll
            for (int c = 0; c < 2; ++c) {
                const float* src = WihD + (size_t)col * (2 * DYN) + c * 32 + 8 * lg;
                a = __builtin_amdgcn_mfma_f32_16x16x32_bf16(
                        aE[c], mk_frag_s(*(const float4*)src, *(const float4*)(src + 4), sj),
                        a, 0, 0, 0);
            }
            xwf[j] = a;
        }
    }

    f32x4 cst = {0.f, 0.f, 0.f, 0.f};
    #pragma unroll 1
    for (int t = 0; t < T_OUT; ++t) {
        const int cur = t & 1, nxt = cur ^ 1;
        const short* rp = &ringD[cur][r][0];
        bf16x8 a_[4];
        #pragma unroll
        for (int c = 0; c < 4; ++c)
            a_[c] = *(const bf16x8*)(rp + (4 * c + lg) * 8);
        f32x4 acc[4];
        #pragma unroll
        for (int j = 0; j < 4; ++j) {
            f32x4 aA = xwf[j];
            f32x4 aB = (f32x4){0.f, 0.f, 0.f, 0.f};
            aA = __builtin_amdgcn_mfma_f32_16x16x32_bf16(a_[0], BfD[j][0], aA, 0, 0, 0);
            aB = __builtin_amdgcn_mfma_f32_16x16x32_bf16(a_[1], BfD[j][1], aB, 0, 0, 0);
            aA = __builtin_amdgcn_mfma_f32_16x16x32_bf16(a_[2], BfD[j][2], aA, 0, 0, 0);
            aB = __builtin_amdgcn_mfma_f32_16x16x32_bf16(a_[3], BfD[j][3], aB, 0, 0, 0);
            acc[j] = aA + aB;
        }
        // inline output head: a_ holds h_state(t) -> fut[t-1]; rotating wave, Bop rebuilt in-branch
        if (t >= 1 && w == ((t - 1) & 7)) {
            f32x4 accO = {0.f, 0.f, 0.f, 0.f};
            #pragma unroll
            for (int c = 0; c < 4; ++c) {
                bf16x8 bo = (bf16x8){0, 0, 0, 0, 0, 0, 0, 0};
                if (r < 2) {
                    float4 f0 = *(const float4*)&wop_s[r][c * 32 + 8 * lg];
                    float4 f1 = *(const float4*)&wop_s[r][c * 32 + 8 * lg + 4];
                    bo = mk_frag(f0, f1);
                }
                accO = __builtin_amdgcn_mfma_f32_16x16x32_bf16(a_[c], bo, accO, 0, 0, 0);
            }
            if (r < 2 && lg < 2) {
                #pragma unroll
                for (int q = 0; q < 4; ++q)
                    fut[((size_t)(t - 1) * BHERO + b0 + 4 * lg + q) * 2 + r] = accO[q] + bop_s[r];
            }
        }
        float hq[4];
        #pragma unroll
        for (int q = 0; q < 4; ++q) {
            float2 hc = cell_update(acc[0][q], acc[1][q], acc[2][q], acc[3][q], cst[q]);
            hq[q]  = hc.x;
            cst[q] = hc.y;
        }
        unsigned u01 = pk2(hq[0], hq[1]), u23 = pk2(hq[2], hq[3]);
        short* wp = &ringD[nxt][4 * lg][u0 + r];
        wp[0 * DROW] = (short)u01; wp[1 * DROW] = (short)(u01 >> 16);
        wp[2 * DROW] = (short)u23; wp[3 * DROW] = (short)(u23 >> 16);
        __syncthreads();                            // h(t+1) ready (slab nxt last read 2 iters ago)
    }

    // ---------------- P5: last output (t = T_OUT-1) from ringD[T_OUT&1] ----------------
    if (w == ((T_OUT - 1) & 7)) {
        const short* rp = &ringD[T_OUT & 1][r][0];
        bf16x8 a_[4];
        #pragma unroll
        for (int c = 0; c < 4; ++c)
            a_[c] = *(const bf16x8*)(rp + (4 * c + lg) * 8);
        f32x4 accO = {0.f, 0.f, 0.f, 0.f};
        #pragma unroll
        for (int c = 0; c < 4; ++c) {
            bf16x8 bo = (bf16x8){0, 0, 0, 0, 0, 0, 0, 0};
            if (r < 2) {
                float4 f0 = *(const float4*)&wop_s[r][c * 32 + 8 * lg];
                float4 f1 = *(const float4*)&wop_s[r][c * 32 + 8 * lg + 4];
                bo = mk_frag(f0, f1);
            }
            accO = __builtin_amdgcn_mfma_f32_16x16x32_bf16(a_[c], bo, accO, 0, 0, 0);
        }
        if (r < 2 && lg < 2) {
            #pragma unroll
            for (int q = 0; q < 4; ++q)
                fut[((size_t)(T_OUT - 1) * BHERO + b0 + 4 * lg + q) * 2 + r] = accO[q] + bop_s[r];
        }
    }
}

extern "C" void kernel_launch(void* const* d_in, const int* in_sizes, int n_in,
                              void* d_out, int out_size, void* d_ws, size_t ws_size,
                              hipStream_t stream) {
    (void)d_ws; (void)ws_size; (void)in_sizes; (void)n_in; (void)out_size;
    const float* hist  = (const float*)d_in[0];
    const float* nbrs  = (const float*)d_in[1];
    const float* Wip   = (const float*)d_in[2];
    const float* bip   = (const float*)d_in[3];
    const float* Wih_e = (const float*)d_in[4];
    const float* Whh_e = (const float*)d_in[5];
    const float* bih_e = (const float*)d_in[6];
    const float* bhh_e = (const float*)d_in[7];
    const float* Wdyn  = (const float*)d_in[8];
    const float* bdyn  = (const float*)d_in[9];
    const float* Wnbr  = (const float*)d_in[10];
    const float* bnbr  = (const float*)d_in[11];
    const float* Wih_d = (const float*)d_in[12];
    const float* Whh_d = (const float*)d_in[13];
    const float* bih_d = (const float*)d_in[14];
    const float* bhh_d = (const float*)d_in[15];
    const float* Wop   = (const float*)d_in[16];
    const float* bop   = (const float*)d_in[17];
    const int*   seg   = (const int*)d_in[18];
    float* fut = (float*)d_out;

    hipLaunchKernelGGL(highway_fused, dim3(BHERO / HEROES), dim3(512), 0, stream,
                       hist, nbrs, Wip, bip, Wih_e, Whh_e, bih_e, bhh_e, Wdyn, bdyn,
                       Wnbr, bnbr, Wih_d, Whh_d, bih_d, bhh_d, Wop, bop, seg, fut);
}

// Round 15
// 108.930 us; speedup vs baseline: 1.3801x; 1.3801x over previous
//
#include <hip/hip_runtime.h>
#include <hip/hip_bf16.h>

#define T_IN   16
#define T_OUT  25
#define BHERO  4096
#define K_NBR  32
#define N_NBR  (BHERO * K_NBR)
#define ENC    64
#define DEC    128
#define DYN    32
#define EMB    32
#define HEROES 8          // real heroes/WG; MFMA A-rows 8-15 stay ZERO (ignored outputs)

#define EMROW  40         // emb row: 32 bf16 + 8 pad (80 B)
#define HROW   72         // encoder h row: 64 bf16 + 8 pad (144 B)
#define RROW   40         // rela row: 32 bf16 + 8 pad (80 B)
#define DROW   136        // decoder h row: 128 bf16 + 8 pad (272 B)

// ---- LDS layout (flat; 46.2 KB -> 2 WGs/CU at 160 KB) ----
#define OFF_HRING  20480
#define OFF_RELA   25088
#define OFF_PMAX   27648
#define OFF_RINGD  31744
#define OFF_ENC    40448
#define OFF_WOP    44800
#define OFF_WIP    45824
#define OFF_BIP    46080
#define OFF_BOP    46208
#define LDS_TOTAL  46216

#define L2E 1.44269504f   // log2(e); gate pre-scales fold the exp-arg mul into W/b

typedef __attribute__((ext_vector_type(8))) short bf16x8;   // 8 bf16 in 4 VGPRs
typedef __attribute__((ext_vector_type(4))) float f32x4;    // MFMA 16x16 C/D frag

__device__ __forceinline__ float lrelu(float x) { return x >= 0.f ? x : 0.1f * x; }
__device__ __forceinline__ float rcpf(float x)  { return __builtin_amdgcn_rcpf(x); }
__device__ __forceinline__ float ex2(float x)   { return __builtin_amdgcn_exp2f(x); }
__device__ __forceinline__ unsigned pk2(float lo, float hi) {
    __hip_bfloat162 p = __float22bfloat162_rn(make_float2(lo, hi));
    unsigned u; __builtin_memcpy(&u, &p, 4); return u;
}
__device__ __forceinline__ bf16x8 mk_frag(float4 f0, float4 f1) {
    uint4 v = { pk2(f0.x, f0.y), pk2(f0.z, f0.w), pk2(f1.x, f1.y), pk2(f1.z, f1.w) };
    bf16x8 r; __builtin_memcpy(&r, &v, 16); return r;
}
__device__ __forceinline__ bf16x8 mk_frag_s(float4 f0, float4 f1, float s) {
    uint4 v = { pk2(f0.x*s, f0.y*s), pk2(f0.z*s, f0.w*s), pk2(f1.x*s, f1.y*s), pk2(f1.z*s, f1.w*s) };
    bf16x8 r; __builtin_memcpy(&r, &v, 16); return r;
}
__device__ __forceinline__ float bf2f(short s) {
    return __uint_as_float(((unsigned)(unsigned short)s) << 16);
}
// Fused LSTM cell update on PRESCALED gates (i,f,o x L2E; g x 2*L2E). 5 exp + 3 rcp.
__device__ __forceinline__ float2 cell_update(float gi, float gf, float gg, float go, float c) {
    float ea = ex2(-gi);
    float ef = ex2(-gf);
    float eb = ex2(-gg);
    float eo = ex2(-go);
    float ff = rcpf(1.f + ef);
    float ig = (1.f - eb) * rcpf((1.f + ea) * (1.f + eb));
    float cc = fmaf(ff, c, ig);
    float ec = ex2(-2.f * L2E * cc);
    float h  = (1.f - ec) * rcpf((1.f + eo) * (1.f + ec));
    return make_float2(h, cc);
}

// ====== fused highwayNet fwd: 512 WGs x 256 threads (4 waves), 8 heroes/WG, 2 WGs/CU ======
// Two INDEPENDENT WGs per CU (independent barriers) -> stall interleaving.
// M=16 MFMA tiles with A-rows 8-15 = zero; output rows 8-15 ignored (row independence).
__global__ __launch_bounds__(256, 2) void highway_fused(
    const float* __restrict__ hist,  const float* __restrict__ nbrs,
    const float* __restrict__ Wip,   const float* __restrict__ bip,
    const float* __restrict__ WihE,  const float* __restrict__ WhhE,
    const float* __restrict__ bihE,  const float* __restrict__ bhhE,
    const float* __restrict__ Wdyn,  const float* __restrict__ bdyn,
    const float* __restrict__ Wnbr,  const float* __restrict__ bnbr,
    const float* __restrict__ WihD,  const float* __restrict__ WhhD,
    const float* __restrict__ bihD,  const float* __restrict__ bhhD,
    const float* __restrict__ Wop,   const float* __restrict__ bop,
    const int*   __restrict__ seg,
    float* __restrict__ fut)                        // [T_OUT][BHERO][2]
{
    __shared__ __align__(16) char lds_raw[LDS_TOTAL];
    auto embs   = (short (*)[16][EMROW])  lds_raw;                  // [16][16][EMROW]
    auto hringE = (short (*)[16][HROW])  (lds_raw + OFF_HRING);     // [2][16][HROW]
    auto rela2  = (short (*)[16][RROW])  (lds_raw + OFF_RELA);      // [2][16][RROW]
    auto pmax   = (float (*)[ENC])       (lds_raw + OFF_PMAX);      // [16][64]
    auto ringD  = (short (*)[16][DROW])  (lds_raw + OFF_RINGD);     // [2][16][DROW]
    auto enc_s  = (float (*)[68])        (lds_raw + OFF_ENC);       // [16][68]
    auto wop_s  = (float (*)[DEC])       (lds_raw + OFF_WOP);       // [2][128]
    auto wip_s  = (float (*)[2])         (lds_raw + OFF_WIP);       // [32][2]
    auto bip_s  = (float*)               (lds_raw + OFF_BIP);       // [32]
    auto bop_s  = (float*)               (lds_raw + OFF_BOP);       // [2]

    const int b0  = blockIdx.x * HEROES;
    const int n0  = blockIdx.x * (HEROES * K_NBR);  // 256 nbr rows per WG
    const int tid = threadIdx.x;
    const int w = tid >> 6, l = tid & 63, r = l & 15, lg = l >> 4;
    const bool valid = (lg < 2);                    // rows 0-7 = real heroes

    // ---------------- P0: consts + zero all M=16 A-buffers (rows 8-15 stay 0 forever) ----------------
    if (tid < EMB) {
        wip_s[tid][0] = Wip[2 * tid];
        wip_s[tid][1] = Wip[2 * tid + 1];
        bip_s[tid]    = bip[tid];
    }
    wop_s[tid >> 7][tid & 127] = Wop[tid];          // 256 = 2*128 exactly
    if (tid < 2) bop_s[tid] = bop[tid];
    for (int i = tid; i < 16 * 16 * EMROW; i += 256) ((short*)embs)[i]   = 0;
    for (int i = tid; i < 2 * 16 * HROW;   i += 256) ((short*)hringE)[i] = 0;
    for (int i = tid; i < 2 * 16 * DROW;   i += 256) ((short*)ringD)[i]  = 0;
    for (int i = tid; i < 16 * 68;         i += 256) ((float*)enc_s)[i]  = 0.f;

    // encoder B-frags (all waves; wave w -> units w*16..+15, 4 gates) + nbr B-frag (col-tile w)
    bf16x8 BfE[4][3];
    float  biasE[4];
    bf16x8 BfN;
    float  biasn;
    #pragma unroll
    for (int j = 0; j < 4; ++j) {
        const float sj  = (j == 2) ? (2.f * L2E) : L2E;
        const int   col = j * ENC + w * 16 + r;
        biasE[j] = (bihE[col] + bhhE[col]) * sj;
        #pragma unroll
        for (int c = 0; c < 3; ++c) {
            const float* src = (c == 0) ? (WihE + (size_t)col * EMB + 8 * lg)
                                        : (WhhE + (size_t)col * ENC + (c - 1) * 32 + 8 * lg);
            BfE[j][c] = mk_frag_s(*(const float4*)src, *(const float4*)(src + 4), sj);
        }
    }
    {
        const int col = w * 16 + r;
        biasn = bnbr[col];
        const float* src = Wnbr + (size_t)col * (2 * T_IN) + 8 * lg;
        BfN = mk_frag(*(const float4*)src, *(const float4*)(src + 4));
    }
    __syncthreads();                                // consts + zeros ready

    // ---------------- P1: emb prefill + rela tile 0 + pipeline prime (all threads) ----------------
    {   // emb: 128 (t,m) tasks x 2 halves
        const int task = tid >> 1;
        const int t = task >> 3, m = task & 7;
        const int j0 = (tid & 1) * 16;
        float2 hv = *(const float2*)&hist[((size_t)t * BHERO + b0 + m) * 2];
        #pragma unroll
        for (int jb = 0; jb < 2; ++jb) {
            float e[8];
            #pragma unroll
            for (int q = 0; q < 8; ++q) {
                int j = j0 + jb * 8 + q;
                e[q] = lrelu(hv.x * wip_s[j][0] + hv.y * wip_s[j][1] + bip_s[j]);
            }
            uint4 v = { pk2(e[0],e[1]), pk2(e[2],e[3]), pk2(e[4],e[5]), pk2(e[6],e[7]) };
            __builtin_memcpy(&embs[t][m][j0 + jb * 8], &v, 16);
        }
    }
    const int nloc = tid & 15;                      // rela task: (nloc, ts)
    const int ts   = tid >> 4;
    float2 c_h0, c_v0;
    int    sg_c;
    {   // tile 0: load + write now
        const int hb = seg[n0 + nloc];
        float2 h0 = *(const float2*)&hist[((size_t)ts * BHERO + hb) * 2];
        float2 v0 = *(const float2*)&nbrs[((size_t)ts * N_NBR + n0 + nloc) * 2];
        ((unsigned*)&rela2[0][nloc][0])[ts] = pk2(h0.x - v0.x, h0.y - v0.y);
    }
    {   // tile 1: issue loads into regs
        const int n  = 16 + nloc;
        const int hb = seg[n0 + n];
        c_h0 = *(const float2*)&hist[((size_t)ts * BHERO + hb) * 2];
        c_v0 = *(const float2*)&nbrs[((size_t)ts * N_NBR + n0 + n) * 2];
    }
    sg_c = seg[n0 + 32 + nloc];                     // seg for tile 2
    f32x4 cstE = {0.f, 0.f, 0.f, 0.f};              // valid lanes: hero 4*lg+q, unit w*16+r
    __syncthreads();                                // emb + rela tile 0 ready

    // ---------------- P2: encoder LSTM + pipelined nbr (all 4 waves do both) ----------------
    #pragma unroll 1
    for (int t = 0; t < T_IN; ++t) {
        const int cur = t & 1, nxt = cur ^ 1;
        // (a) issue tile t+2 loads; prefetch seg for t+3
        float2 n_h0 = {}, n_v0 = {};
        int    sg_n = 0;
        if (t < T_IN - 2) {
            const int n = 16 * (t + 2) + nloc;
            n_h0 = *(const float2*)&hist[((size_t)ts * BHERO + sg_c) * 2];
            n_v0 = *(const float2*)&nbrs[((size_t)ts * N_NBR + n0 + n) * 2];
        }
        if (t < T_IN - 3) sg_n = seg[n0 + 16 * (t + 3) + nloc];
        // (b) write tile t+1 from regs (HBM latency hidden under previous interval)
        if (t < T_IN - 1)
            ((unsigned*)&rela2[nxt][nloc][0])[ts] = pk2(c_h0.x - c_v0.x, c_h0.y - c_v0.y);
        // (c) encoder step: 12 MFMAs + nonlin (valid lanes only)
        {
            bf16x8 a0 = *(const bf16x8*)&embs[t][r][8 * lg];
            bf16x8 a1 = *(const bf16x8*)&hringE[cur][r][8 * lg];
            bf16x8 a2 = *(const bf16x8*)&hringE[cur][r][32 + 8 * lg];
            f32x4 acc[4];
            #pragma unroll
            for (int j = 0; j < 4; ++j) {
                f32x4 aA = (f32x4){biasE[j], biasE[j], biasE[j], biasE[j]};
                f32x4 aB = (f32x4){0.f, 0.f, 0.f, 0.f};
                aA = __builtin_amdgcn_mfma_f32_16x16x32_bf16(a0, BfE[j][0], aA, 0, 0, 0);
                aB = __builtin_amdgcn_mfma_f32_16x16x32_bf16(a1, BfE[j][1], aB, 0, 0, 0);
                aA = __builtin_amdgcn_mfma_f32_16x16x32_bf16(a2, BfE[j][2], aA, 0, 0, 0);
                acc[j] = aA + aB;
            }
            if (valid) {
                #pragma unroll
                for (int q = 0; q < 4; ++q) {
                    float2 hc = cell_update(acc[0][q], acc[1][q], acc[2][q], acc[3][q], cstE[q]);
                    cstE[q] = hc.y;
                    hringE[nxt][4 * lg + q][w * 16 + r] = (short)(pk2(hc.x, 0.f) & 0xFFFF);
                }
            }
        }
        // (d) nbr GEMM tile t (staged last interval): wave w -> col-tile w
        {
            bf16x8 a = *(const bf16x8*)&rela2[cur][r][8 * lg];
            f32x4 accN = {biasn, biasn, biasn, biasn};
            accN = __builtin_amdgcn_mfma_f32_16x16x32_bf16(a, BfN, accN, 0, 0, 0);
            float m4 = fmaxf(fmaxf(accN[0], accN[1]), fmaxf(accN[2], accN[3]));
            m4 = fmaxf(m4, __shfl_xor(m4, 16));
            m4 = fmaxf(m4, __shfl_xor(m4, 32));
            if (l < 16) pmax[t][w * 16 + r] = m4;
        }
        c_h0 = n_h0; c_v0 = n_v0; sg_c = sg_n;
        __syncthreads();                            // h(t+1) + tile t+1 + pmax t ready
    }

    // ---------------- P3: enc_s = [hist_e | scene_d] (rows 0-7; 8-15 stay 0) ----------------
    #pragma unroll
    for (int it = 0; it < 2; ++it) {
        const int s = tid + 256 * it;               // 512 tasks: (m 0..7, col 0..63)
        const int m = s >> 6, col = s & 63;
        const float* wd = Wdyn + (size_t)(col & 31) * ENC;
        float a = bdyn[col & 31];
        if (col < 32) {
            const short* hp = &hringE[0][m][0];     // final h in slab 0 after 16 flips
            #pragma unroll
            for (int kb = 0; kb < 8; ++kb) {
                bf16x8 hv = *(const bf16x8*)(hp + kb * 8);
                #pragma unroll
                for (int e = 0; e < 8; ++e)
                    a = fmaf(bf2f(hv[e]), wd[kb * 8 + e], a);
            }
        } else {
            #pragma unroll
            for (int kb = 0; kb < 16; ++kb) {
                float4 p0 = *(const float4*)&pmax[2 * m][kb * 4];
                float4 p1 = *(const float4*)&pmax[2 * m + 1][kb * 4];
                a = fmaf(lrelu(fmaxf(p0.x, p1.x)), wd[kb * 4 + 0], a);
                a = fmaf(lrelu(fmaxf(p0.y, p1.y)), wd[kb * 4 + 1], a);
                a = fmaf(lrelu(fmaxf(p0.z, p1.z)), wd[kb * 4 + 2], a);
                a = fmaf(lrelu(fmaxf(p0.w, p1.w)), wd[kb * 4 + 3], a);
            }
        }
        enc_s[m][col] = lrelu(a);
    }
    __syncthreads();                                // enc_s ready (ringD already zeroed in P0)

    // ---------------- P4: decoder — 8 tiles/wave (2 unit-blocks x 4 gates), inline head ----------------
    bf16x8 BfD[2][4][4];                            // [ub2][gate][chunk] = 128 VGPRs
    float  biasD[2][4];
    #pragma unroll
    for (int u2 = 0; u2 < 2; ++u2) {
        #pragma unroll
        for (int j = 0; j < 4; ++j) {
            const float sj  = (j == 2) ? (2.f * L2E) : L2E;
            const int   col = j * DEC + (2 * w + u2) * 16 + r;
            biasD[u2][j] = (bihD[col] + bhhD[col]) * sj;
            #pragma unroll
            for (int c = 0; c < 4; ++c) {
                const float* src = WhhD + (size_t)col * DEC + c * 32 + 8 * lg;
                BfD[u2][j][c] = mk_frag_s(*(const float4*)src, *(const float4*)(src + 4), sj);
            }
        }
    }
    f32x4 xwf[2][4];
    {
        bf16x8 aE[2];
        #pragma unroll
        for (int c = 0; c < 2; ++c) {
            float4 f0 = *(const float4*)&enc_s[r][c * 32 + 8 * lg];
            float4 f1 = *(const float4*)&enc_s[r][c * 32 + 8 * lg + 4];
            aE[c] = mk_frag(f0, f1);
        }
        #pragma unroll
        for (int u2 = 0; u2 < 2; ++u2) {
            #pragma unroll
            for (int j = 0; j < 4; ++j) {
                const float sj  = (j == 2) ? (2.f * L2E) : L2E;
                const int   col = j * DEC + (2 * w + u2) * 16 + r;
                f32x4 a = {biasD[u2][j], biasD[u2][j], biasD[u2][j], biasD[u2][j]};
                #pragma unroll
                for (int c = 0; c < 2; ++c) {
                    const float* src = WihD + (size_t)col * (2 * DYN) + c * 32 + 8 * lg;
                    a = __builtin_amdgcn_mfma_f32_16x16x32_bf16(
                            aE[c], mk_frag_s(*(const float4*)src, *(const float4*)(src + 4), sj),
                            a, 0, 0, 0);
                }
                xwf[u2][j] = a;
            }
        }
    }

    f32x4 cstA = {0.f, 0.f, 0.f, 0.f};              // cells for ub2=0 (valid lanes)
    f32x4 cstB = {0.f, 0.f, 0.f, 0.f};              // cells for ub2=1
    #pragma unroll 1
    for (int t = 0; t < T_OUT; ++t) {
        const int cur = t & 1, nxt = cur ^ 1;
        const short* rp = &ringD[cur][r][0];
        bf16x8 a_[4];
        #pragma unroll
        for (int c = 0; c < 4; ++c)
            a_[c] = *(const bf16x8*)(rp + (4 * c + lg) * 8);
        f32x4 acc[2][4];
        #pragma unroll
        for (int u2 = 0; u2 < 2; ++u2) {
            #pragma unroll
            for (int j = 0; j < 4; ++j) {
                f32x4 aA = xwf[u2][j];
                f32x4 aB = (f32x4){0.f, 0.f, 0.f, 0.f};
                aA = __builtin_amdgcn_mfma_f32_16x16x32_bf16(a_[0], BfD[u2][j][0], aA, 0, 0, 0);
                aB = __builtin_amdgcn_mfma_f32_16x16x32_bf16(a_[1], BfD[u2][j][1], aB, 0, 0, 0);
                aA = __builtin_amdgcn_mfma_f32_16x16x32_bf16(a_[2], BfD[u2][j][2], aA, 0, 0, 0);
                aB = __builtin_amdgcn_mfma_f32_16x16x32_bf16(a_[3], BfD[u2][j][3], aB, 0, 0, 0);
                acc[u2][j] = aA + aB;
            }
        }
        // inline output head: a_ holds h_state(t) -> fut[t-1]; rotating wave
        if (t >= 1 && w == ((t - 1) & 3)) {
            f32x4 accO = {0.f, 0.f, 0.f, 0.f};
            #pragma unroll
            for (int c = 0; c < 4; ++c) {
                bf16x8 bo = (bf16x8){0, 0, 0, 0, 0, 0, 0, 0};
                if (r < 2) {
                    float4 f0 = *(const float4*)&wop_s[r][c * 32 + 8 * lg];
                    float4 f1 = *(const float4*)&wop_s[r][c * 32 + 8 * lg + 4];
                    bo = mk_frag(f0, f1);
                }
                accO = __builtin_amdgcn_mfma_f32_16x16x32_bf16(a_[c], bo, accO, 0, 0, 0);
            }
            if (r < 2 && lg < 2) {
                #pragma unroll
                for (int q = 0; q < 4; ++q)
                    fut[((size_t)(t - 1) * BHERO + b0 + 4 * lg + q) * 2 + r] = accO[q] + bop_s[r];
            }
        }
        if (valid) {
            #pragma unroll
            for (int q = 0; q < 4; ++q) {
                float2 hcA = cell_update(acc[0][0][q], acc[0][1][q], acc[0][2][q], acc[0][3][q], cstA[q]);
                float2 hcB = cell_update(acc[1][0][q], acc[1][1][q], acc[1][2][q], acc[1][3][q], cstB[q]);
                cstA[q] = hcA.y;
                cstB[q] = hcB.y;
                short* row = &ringD[nxt][4 * lg + q][0];
                row[(2 * w + 0) * 16 + r] = (short)(pk2(hcA.x, 0.f) & 0xFFFF);
                row[(2 * w + 1) * 16 + r] = (short)(pk2(hcB.x, 0.f) & 0xFFFF);
            }
        }
        __syncthreads();                            // h(t+1) ready (slab nxt last read 2 iters ago)
    }

    // ---------------- P5: last output (t = T_OUT-1) from ringD[T_OUT&1] ----------------
    if (w == ((T_OUT - 1) & 3)) {
        const short* rp = &ringD[T_OUT & 1][r][0];
        bf16x8 a_[4];
        #pragma unroll
        for (int c = 0; c < 4; ++c)
            a_[c] = *(const bf16x8*)(rp + (4 * c + lg) * 8);
        f32x4 accO = {0.f, 0.f, 0.f, 0.f};
        #pragma unroll
        for (int c = 0; c < 4; ++c) {
            bf16x8 bo = (bf16x8){0, 0, 0, 0, 0, 0, 0, 0};
            if (r < 2) {
                float4 f0 = *(const float4*)&wop_s[r][c * 32 + 8 * lg];
                float4 f1 = *(const float4*)&wop_s[r][c * 32 + 8 * lg + 4];
                bo = mk_frag(f0, f1);
            }
            accO = __builtin_amdgcn_mfma_f32_16x16x32_bf16(a_[c], bo, accO, 0, 0, 0);
        }
        if (r < 2 && lg < 2) {
            #pragma unroll
            for (int q = 0; q < 4; ++q)
                fut[((size_t)(T_OUT - 1) * BHERO + b0 + 4 * lg + q) * 2 + r] = accO[q] + bop_s[r];
        }
    }
}

extern "C" void kernel_launch(void* const* d_in, const int* in_sizes, int n_in,
                              void* d_out, int out_size, void* d_ws, size_t ws_size,
                              hipStream_t stream) {
    (void)d_ws; (void)ws_size; (void)in_sizes; (void)n_in; (void)out_size;
    const float* hist  = (const float*)d_in[0];
    const float* nbrs  = (const float*)d_in[1];
    const float* Wip   = (const float*)d_in[2];
    const float* bip   = (const float*)d_in[3];
    const float* Wih_e = (const float*)d_in[4];
    const float* Whh_e = (const float*)d_in[5];
    const float* bih_e = (const float*)d_in[6];
    const float* bhh_e = (const float*)d_in[7];
    const float* Wdyn  = (const float*)d_in[8];
    const float* bdyn  = (const float*)d_in[9];
    const float* Wnbr  = (const float*)d_in[10];
    const float* bnbr  = (const float*)d_in[11];
    const float* Wih_d = (const float*)d_in[12];
    const float* Whh_d = (const float*)d_in[13];
    const float* bih_d = (const float*)d_in[14];
    const float* bhh_d = (const float*)d_in[15];
    const float* Wop   = (const float*)d_in[16];
    const float* bop   = (const float*)d_in[17];
    const int*   seg   = (const int*)d_in[18];
    float* fut = (float*)d_out;

    hipLaunchKernelGGL(highway_fused, dim3(BHERO / HEROES), dim3(256), 0, stream,
                       hist, nbrs, Wip, bip, Wih_e, Whh_e, bih_e, bhh_e, Wdyn, bdyn,
                       Wnbr, bnbr, Wih_d, Whh_d, bih_d, bhh_d, Wop, bop, seg, fut);
}